// Round 1
// baseline (89.238 us; speedup 1.0000x reference)
//
#include <hip/hip_runtime.h>

#define N 512
#define MARGIN 0.2f
#define BLOCK 256

// ws layout: ws[0] = sum of means, ws[1] = count of valid rows/cols
__global__ void rk_init(float* ws) {
    if (threadIdx.x < 2) ws[threadIdx.x] = 0.0f;
}

__global__ __launch_bounds__(BLOCK) void rk_main(const float* __restrict__ scores,
                                                 const int* __restrict__ labels,
                                                 float* __restrict__ ws) {
    __shared__ float pos_s[N];
    __shared__ float neg_s[N];
    __shared__ int cnt_pos, cnt_neg;
    __shared__ float red[BLOCK / 64];

    const int b = blockIdx.x;
    const bool colside = (b >= N);
    const int n = colside ? (b - N) : b;
    const int tid = threadIdx.x;

    if (tid == 0) { cnt_pos = 0; cnt_neg = 0; }
    __syncthreads();

    // Load this row (or column) and compact into pos/neg score lists.
    for (int m = tid; m < N; m += BLOCK) {
        float s;
        int lab;
        if (!colside) {
            s   = scores[n * N + m];
            lab = labels[n * N + m];
        } else {
            s   = scores[m * N + n];
            lab = labels[m * N + n];
        }
        if (lab == 1) {
            int p = atomicAdd(&cnt_pos, 1);
            pos_s[p] = s;
        } else {
            int p = atomicAdd(&cnt_neg, 1);
            neg_s[p] = s;
        }
    }
    __syncthreads();

    const int np = cnt_pos;
    const int nn = cnt_neg;

    // tot = sum over (pos i, neg j) of relu(MARGIN + s_j - s_i)
    float tot = 0.0f;
    for (int i = tid; i < np; i += BLOCK) {
        const float base = MARGIN - pos_s[i];
        float acc = 0.0f;
        for (int j = 0; j < nn; ++j) {
            acc += fmaxf(base + neg_s[j], 0.0f);  // LDS broadcast read
        }
        tot += acc;
    }

    // wave (64-lane) shuffle reduction
    for (int off = 32; off > 0; off >>= 1)
        tot += __shfl_down(tot, off, 64);

    const int wave = tid >> 6;
    const int lane = tid & 63;
    if (lane == 0) red[wave] = tot;
    __syncthreads();

    if (tid == 0) {
        float t = 0.0f;
        for (int w = 0; w < BLOCK / 64; ++w) t += red[w];
        const long long cnt = (long long)np * (long long)nn;
        const float mean = (cnt > 0) ? (t / (float)cnt) : 0.0f;
        atomicAdd(&ws[0], mean);
        atomicAdd(&ws[1], (cnt > 0) ? 1.0f : 0.0f);
    }
}

__global__ void rk_finalize(const float* __restrict__ ws, float* __restrict__ out) {
    if (threadIdx.x == 0 && blockIdx.x == 0) {
        out[0] = ws[0] / ws[1];
    }
}

extern "C" void kernel_launch(void* const* d_in, const int* in_sizes, int n_in,
                              void* d_out, int out_size, void* d_ws, size_t ws_size,
                              hipStream_t stream) {
    const float* scores = (const float*)d_in[0];
    const int*   labels = (const int*)d_in[1];
    float* out = (float*)d_out;
    float* ws  = (float*)d_ws;

    rk_init<<<1, 64, 0, stream>>>(ws);
    rk_main<<<2 * N, BLOCK, 0, stream>>>(scores, labels, ws);
    rk_finalize<<<1, 64, 0, stream>>>(ws, out);
}

// Round 2
// 69.098 us; speedup vs baseline: 1.2915x; 1.2915x over previous
//
#include <hip/hip_runtime.h>

#define N 512
#define MARGIN 0.2f
#define BLOCK 256
#define NBLOCKS (2 * N)

// ws layout: float2 per block: (row/col mean, valid flag). Plain stores -> no init kernel.
__global__ __launch_bounds__(BLOCK) void rk_main(const float* __restrict__ scores,
                                                 const int* __restrict__ labels,
                                                 float2* __restrict__ ws) {
    __shared__ __align__(16) float pos_s[N];
    __shared__ __align__(16) float neg_s[N];
    __shared__ int cnt_pos, cnt_neg;
    __shared__ float red[BLOCK / 64];

    const int b = blockIdx.x;
    const int tid = threadIdx.x;
    const int lane = tid & 63;
    const int wave = tid >> 6;
    const bool colside = (b >= N);
    const int n = colside ? (b - N) : b;

    if (tid == 0) { cnt_pos = 0; cnt_neg = 0; }

    // Each thread loads two elements of the row (or column).
    const int m0 = tid, m1 = tid + BLOCK;
    float s0, s1;
    int l0, l1;
    if (!colside) {
        s0 = scores[n * N + m0]; l0 = labels[n * N + m0];
        s1 = scores[n * N + m1]; l1 = labels[n * N + m1];
    } else {
        s0 = scores[m0 * N + n]; l0 = labels[m0 * N + n];
        s1 = scores[m1 * N + n]; l1 = labels[m1 * N + n];
    }
    __syncthreads();  // cnt init visible before wave atomics

    // Ballot-based compaction: one atomic per wave instead of 512 per block.
    const unsigned long long mp0 = __ballot(l0 == 1);
    const unsigned long long mp1 = __ballot(l1 == 1);
    const unsigned long long below = (1ull << lane) - 1ull;
    const int cp0 = __popcll(mp0), cp1 = __popcll(mp1);

    int bp = 0, bn = 0;
    if (lane == 0) {
        bp = atomicAdd(&cnt_pos, cp0 + cp1);
        bn = atomicAdd(&cnt_neg, (64 - cp0) + (64 - cp1));
    }
    bp = __shfl(bp, 0, 64);
    bn = __shfl(bn, 0, 64);

    // Pre-add the margin into neg scores: term = max(neg' - s_pos, 0).
    if (l0 == 1) pos_s[bp + __popcll(mp0 & below)] = s0;
    else         neg_s[bn + __popcll(~mp0 & below)] = MARGIN + s0;
    if (l1 == 1) pos_s[bp + cp0 + __popcll(mp1 & below)] = s1;
    else         neg_s[bn + (64 - cp0) + __popcll(~mp1 & below)] = MARGIN + s1;

    __syncthreads();
    const int np = cnt_pos, nn = cnt_neg;
    const int npp = (np + 255) & ~255;  // pos padded to mult of 256 (max 512)
    const int nnp = (nn + 15) & ~15;    // neg padded to mult of 16  (max 512)
    // Sentinels make padded entries contribute exactly 0 to the relu sum.
    for (int i = np + tid; i < npp; i += BLOCK) pos_s[i] = 1e30f;
    for (int j = nn + tid; j < nnp; j += BLOCK) neg_s[j] = -1e30f;
    __syncthreads();

    // Inner loop: each wave owns a quarter of the neg range (float4-aligned),
    // each lane register-tiles 4 pos values -> 16 pairs per ds_read_b128.
    const float4* neg4 = (const float4*)neg_s;
    const int jq4 = nnp >> 4;  // float4s per wave-quarter
    const int jbeg = wave * jq4, jend = jbeg + jq4;

    float tot = 0.0f;
    for (int c = 0; c < npp; c += 256) {
        const float si0 = pos_s[c + lane];
        const float si1 = pos_s[c + 64 + lane];
        const float si2 = pos_s[c + 128 + lane];
        const float si3 = pos_s[c + 192 + lane];
        float a0 = 0.f, a1 = 0.f, a2 = 0.f, a3 = 0.f;
        for (int jj = jbeg; jj < jend; ++jj) {
            const float4 v = neg4[jj];  // wave-uniform broadcast read
            a0 += fmaxf(v.x - si0, 0.f); a1 += fmaxf(v.x - si1, 0.f);
            a2 += fmaxf(v.x - si2, 0.f); a3 += fmaxf(v.x - si3, 0.f);
            a0 += fmaxf(v.y - si0, 0.f); a1 += fmaxf(v.y - si1, 0.f);
            a2 += fmaxf(v.y - si2, 0.f); a3 += fmaxf(v.y - si3, 0.f);
            a0 += fmaxf(v.z - si0, 0.f); a1 += fmaxf(v.z - si1, 0.f);
            a2 += fmaxf(v.z - si2, 0.f); a3 += fmaxf(v.z - si3, 0.f);
            a0 += fmaxf(v.w - si0, 0.f); a1 += fmaxf(v.w - si1, 0.f);
            a2 += fmaxf(v.w - si2, 0.f); a3 += fmaxf(v.w - si3, 0.f);
        }
        tot += (a0 + a1) + (a2 + a3);
    }

    // Wave shuffle reduce, then block reduce.
    for (int off = 32; off > 0; off >>= 1) tot += __shfl_down(tot, off, 64);
    if (lane == 0) red[wave] = tot;
    __syncthreads();

    if (tid == 0) {
        const float t = red[0] + red[1] + red[2] + red[3];
        const float cnt = (float)np * (float)nn;
        float2 r;
        r.x = (cnt > 0.f) ? t / cnt : 0.f;
        r.y = (cnt > 0.f) ? 1.f : 0.f;
        ws[b] = r;
    }
}

__global__ __launch_bounds__(BLOCK) void rk_finalize(const float2* __restrict__ ws,
                                                     float* __restrict__ out) {
    __shared__ float2 red[BLOCK / 64];
    const int tid = threadIdx.x;
    const int lane = tid & 63;
    const int wave = tid >> 6;

    float sm = 0.f, sv = 0.f;
    for (int i = tid; i < NBLOCKS; i += BLOCK) {
        const float2 v = ws[i];
        sm += v.x;
        sv += v.y;
    }
    for (int off = 32; off > 0; off >>= 1) {
        sm += __shfl_down(sm, off, 64);
        sv += __shfl_down(sv, off, 64);
    }
    if (lane == 0) red[wave] = make_float2(sm, sv);
    __syncthreads();

    if (tid == 0) {
        float tm = 0.f, tv = 0.f;
        for (int w = 0; w < BLOCK / 64; ++w) { tm += red[w].x; tv += red[w].y; }
        out[0] = tm / tv;
    }
}

extern "C" void kernel_launch(void* const* d_in, const int* in_sizes, int n_in,
                              void* d_out, int out_size, void* d_ws, size_t ws_size,
                              hipStream_t stream) {
    const float* scores = (const float*)d_in[0];
    const int*   labels = (const int*)d_in[1];
    float* out = (float*)d_out;
    float2* ws = (float2*)d_ws;

    rk_main<<<NBLOCKS, BLOCK, 0, stream>>>(scores, labels, ws);
    rk_finalize<<<1, BLOCK, 0, stream>>>(ws, out);
}